// Round 3
// baseline (811.067 us; speedup 1.0000x reference)
//
#include <hip/hip_runtime.h>
#include <hip/hip_bf16.h>

using short8  = __attribute__((ext_vector_type(8))) short;
using float4v = __attribute__((ext_vector_type(4))) float;

#define MFMA(a,b,cc) __builtin_amdgcn_mfma_f32_16x16x32_bf16((a),(b),(cc),0,0,0)
// barrier WITHOUT vmcnt drain: LDS writes flushed, global prefetch stays in flight
#define PIPE_BARRIER() asm volatile("s_waitcnt lgkmcnt(0)\n\ts_barrier" ::: "memory")

static __device__ __forceinline__ float fexp2(float x){ return __builtin_amdgcn_exp2f(x); }
static __device__ __forceinline__ float frcp(float x){ return __builtin_amdgcn_rcpf(x); }
#define LOG2E 1.44269504088896340736f

static __device__ __forceinline__ short f2bf(float f){
  __hip_bfloat16 h = __float2bfloat16(f);
  return __builtin_bit_cast(short, h);
}
static __device__ __forceinline__ short8 load_bf8(const float* p){
  short8 v;
#pragma unroll
  for (int j = 0; j < 8; ++j) v[j] = f2bf(p[j]);
  return v;
}

// per-lane gate math: lane holds i,f,g,o for ONE unit x 4 batch rows. No shuffles.
static __device__ __forceinline__ void gate4(const float4v& ai, const float4v& af,
                                             const float4v& ag, const float4v& ao,
                                             float (&cst)[4], float (&hv)[4]){
#pragma unroll
  for (int r = 0; r < 4; ++r){
    float iv = frcp(1.f + fexp2(-LOG2E * ai[r]));
    float fv = frcp(1.f + fexp2(-LOG2E * af[r]));
    float ov = frcp(1.f + fexp2(-LOG2E * ao[r]));
    float gv = 1.f - 2.f * frcp(1.f + fexp2((2.f*LOG2E) * ag[r]));   // tanh
    float cn = fv * cst[r] + iv * gv;
    cst[r] = cn;
    float tc = 1.f - 2.f * frcp(1.f + fexp2((2.f*LOG2E) * cn));      // tanh
    hv[r] = ov * tc;
  }
}

// ---- layer-0 step, TPAR = t&1 (selects h double-buffer statically) ----
template<int TPAR>
static __device__ __forceinline__ void l0_step(int t, const float* xrow,
    float4v (&xc)[4][2],
    const short8 (&wi)[4][4], const short8 (&wh)[4][2], const float (&bs)[4],
    float (&cst)[4], __hip_bfloat16 (&h0s)[2][16][72],
    int c, int kg, int wl)
{
  constexpr int WB = TPAR, RB = TPAR ^ 1;
  // issue h read early (latency overlaps input MFMAs)
  short8 hf0 = *(const short8*)&h0s[RB][c][kg*8];
  short8 hf1 = *(const short8*)&h0s[RB][c][32 + kg*8];
  // convert prefetched x_t
  short8 xb[4];
#pragma unroll
  for (int kk = 0; kk < 4; ++kk){
#pragma unroll
    for (int j = 0; j < 4; ++j){ xb[kk][j] = f2bf(xc[kk][0][j]); xb[kk][4+j] = f2bf(xc[kk][1][j]); }
  }
  // issue prefetch for t+2 (drains only at its use, 2 barriers later)
  if (t + 2 < 512){
    const float* nx = xrow + (size_t)(t + 2) * 128;
#pragma unroll
    for (int kk = 0; kk < 4; ++kk){
      xc[kk][0] = *(const float4v*)(nx + kk*32);
      xc[kk][1] = *(const float4v*)(nx + kk*32 + 4);
    }
  }
  float4v ai = {bs[0],bs[0],bs[0],bs[0]};
  float4v af = {bs[1],bs[1],bs[1],bs[1]};
  float4v ag = {bs[2],bs[2],bs[2],bs[2]};
  float4v ao = {bs[3],bs[3],bs[3],bs[3]};
#pragma unroll
  for (int kk = 0; kk < 4; ++kk){
    ai = MFMA(xb[kk], wi[0][kk], ai);
    af = MFMA(xb[kk], wi[1][kk], af);
    ag = MFMA(xb[kk], wi[2][kk], ag);
    ao = MFMA(xb[kk], wi[3][kk], ao);
  }
  ai = MFMA(hf0, wh[0][0], ai); af = MFMA(hf0, wh[1][0], af);
  ag = MFMA(hf0, wh[2][0], ag); ao = MFMA(hf0, wh[3][0], ao);
  ai = MFMA(hf1, wh[0][1], ai); af = MFMA(hf1, wh[1][1], af);
  ag = MFMA(hf1, wh[2][1], ag); ao = MFMA(hf1, wh[3][1], ao);
  float hv[4];
  gate4(ai, af, ag, ao, cst, hv);
#pragma unroll
  for (int r = 0; r < 4; ++r)
    h0s[WB][kg*4 + r][wl*16 + c] = __float2bfloat16(hv[r]);
}

// ---- layer-1 step, TPAR = t1&1 ----
template<int TPAR>
static __device__ __forceinline__ void l1_step(bool last,
    const short8 (&wi)[4][4], const short8 (&wh)[4][2], const float (&bs)[4],
    float (&cst)[4],
    const __hip_bfloat16 (&h0s)[2][16][72], __hip_bfloat16 (&h1s)[2][16][72],
    float (*hfin)[64], int c, int kg, int wl)
{
  constexpr int WB = TPAR, RB = TPAR ^ 1;
  short8 a0 = *(const short8*)&h0s[TPAR][c][kg*8];      // h0[t1]
  short8 a1 = *(const short8*)&h0s[TPAR][c][32 + kg*8];
  short8 b0 = *(const short8*)&h1s[RB][c][kg*8];        // h1[t1-1]
  short8 b1 = *(const short8*)&h1s[RB][c][32 + kg*8];
  float4v ai = {bs[0],bs[0],bs[0],bs[0]};
  float4v af = {bs[1],bs[1],bs[1],bs[1]};
  float4v ag = {bs[2],bs[2],bs[2],bs[2]};
  float4v ao = {bs[3],bs[3],bs[3],bs[3]};
  ai = MFMA(a0, wi[0][0], ai); af = MFMA(a0, wi[1][0], af);
  ag = MFMA(a0, wi[2][0], ag); ao = MFMA(a0, wi[3][0], ao);
  ai = MFMA(a1, wi[0][1], ai); af = MFMA(a1, wi[1][1], af);
  ag = MFMA(a1, wi[2][1], ag); ao = MFMA(a1, wi[3][1], ao);
  ai = MFMA(b0, wh[0][0], ai); af = MFMA(b0, wh[1][0], af);
  ag = MFMA(b0, wh[2][0], ag); ao = MFMA(b0, wh[3][0], ao);
  ai = MFMA(b1, wh[0][1], ai); af = MFMA(b1, wh[1][1], af);
  ag = MFMA(b1, wh[2][1], ag); ao = MFMA(b1, wh[3][1], ao);
  float hv[4];
  gate4(ai, af, ag, ao, cst, hv);
#pragma unroll
  for (int r = 0; r < 4; ++r){
    h1s[WB][kg*4 + r][wl*16 + c] = __float2bfloat16(hv[r]);
    if (last) hfin[kg*4 + r][wl*16 + c] = hv[r];
  }
}

// Fused 2-layer LSTM: waves 0-3 = layer0 (step t), waves 4-7 = layer1 (step t-1).
// Raw s_barrier (lgkm-only drain) so x prefetch stays in flight across barriers.
__global__ __launch_bounds__(512, 2) void lstm2_pipe3(
    const float* __restrict__ x,
    const float* __restrict__ Wih0, const float* __restrict__ Whh0,
    const float* __restrict__ bih0, const float* __restrict__ bhh0,
    const float* __restrict__ Wih1, const float* __restrict__ Whh1,
    const float* __restrict__ bih1, const float* __restrict__ bhh1,
    const float* __restrict__ fcw,  const float* __restrict__ fcb,
    float* __restrict__ out)
{
  constexpr int T = 512, DIN = 128;
  const int tid  = threadIdx.x;
  const int lane = tid & 63;
  const int wv   = tid >> 6;
  const int grp  = wv >> 2;     // 0: layer0, 1: layer1
  const int wl   = wv & 3;      // wave within group: owns units [16wl,16wl+16)
  const int c    = lane & 15;
  const int kg   = lane >> 4;
  const int bstart = blockIdx.x << 4;

  __shared__ __align__(16) __hip_bfloat16 h0s[2][16][72];
  __shared__ __align__(16) __hip_bfloat16 h1s[2][16][72];
  __shared__ float hfin[16][64];

  {
    __hip_bfloat16 z = __float2bfloat16(0.f);
    for (int i = tid; i < 2*16*72; i += 512){
      (&h0s[0][0][0])[i] = z;
      (&h1s[0][0][0])[i] = z;
    }
  }

  // weight fragments: tile = same-gate 16 units. row = gt*64 + wl*16 + c.
  short8 wi[4][4];   // grp0: Wih0 (K=128, 4 frags); grp1: Wih1 (K=64, frags 0-1)
  short8 wh[4][2];   // grp0: Whh0; grp1: Whh1
  float  bs[4];
  const int urow = wl*16 + c;
  if (grp == 0){
#pragma unroll
    for (int gt = 0; gt < 4; ++gt){
      const int row = gt*64 + urow;
#pragma unroll
      for (int kk = 0; kk < 4; ++kk)
        wi[gt][kk] = load_bf8(Wih0 + row*128 + kk*32 + kg*8);
#pragma unroll
      for (int kk = 0; kk < 2; ++kk)
        wh[gt][kk] = load_bf8(Whh0 + row*64 + kk*32 + kg*8);
      bs[gt] = bih0[row] + bhh0[row];
    }
  } else {
#pragma unroll
    for (int gt = 0; gt < 4; ++gt){
      const int row = gt*64 + urow;
#pragma unroll
      for (int kk = 0; kk < 2; ++kk){
        wi[gt][kk] = load_bf8(Wih1 + row*64 + kk*32 + kg*8);
        wh[gt][kk] = load_bf8(Whh1 + row*64 + kk*32 + kg*8);
      }
      bs[gt] = bih1[row] + bhh1[row];
    }
  }

  // x double-buffer (even t -> xrA, odd t -> xrB), depth-2 prefetch
  const float* xrow = nullptr;
  float4v xrA[4][2], xrB[4][2];
  if (grp == 0){
    xrow = x + (size_t)(bstart + c) * T * DIN + kg*8;
#pragma unroll
    for (int kk = 0; kk < 4; ++kk){
      xrA[kk][0] = *(const float4v*)(xrow + kk*32);
      xrA[kk][1] = *(const float4v*)(xrow + kk*32 + 4);
      xrB[kk][0] = *(const float4v*)(xrow + DIN + kk*32);
      xrB[kk][1] = *(const float4v*)(xrow + DIN + kk*32 + 4);
    }
  }
  float cst[4] = {0.f, 0.f, 0.f, 0.f};

  __syncthreads();  // init + weight loads (once)

  // prologue: t=0
  if (grp == 0) l0_step<0>(0, xrow, xrA, wi, wh, bs, cst, h0s, c, kg, wl);
  PIPE_BARRIER();
  // t=1 / t1=0
  if (grp == 0) l0_step<1>(1, xrow, xrB, wi, wh, bs, cst, h0s, c, kg, wl);
  else          l1_step<0>(false, wi, wh, bs, cst, h0s, h1s, hfin, c, kg, wl);
  PIPE_BARRIER();

  for (int it = 2; it < T; it += 2){
    // even window: L0 t=it, L1 t1=it-1 (odd)
    if (grp == 0) l0_step<0>(it, xrow, xrA, wi, wh, bs, cst, h0s, c, kg, wl);
    else          l1_step<1>(false, wi, wh, bs, cst, h0s, h1s, hfin, c, kg, wl);
    PIPE_BARRIER();
    // odd window: L0 t=it+1, L1 t1=it (even)
    if (grp == 0) l0_step<1>(it+1, xrow, xrB, wi, wh, bs, cst, h0s, c, kg, wl);
    else          l1_step<0>(false, wi, wh, bs, cst, h0s, h1s, hfin, c, kg, wl);
    PIPE_BARRIER();
  }
  // epilogue: t1 = 511 (odd)
  if (grp == 1) l1_step<1>(true, wi, wh, bs, cst, h0s, h1s, hfin, c, kg, wl);
  __syncthreads();

  if (tid < 16){
    float s = fcb[0];
#pragma unroll
    for (int k = 0; k < 64; ++k) s += hfin[tid][k] * fcw[k];
    out[bstart + tid] = frcp(1.f + fexp2(-LOG2E * s));
  }
}

extern "C" void kernel_launch(void* const* d_in, const int* in_sizes, int n_in,
                              void* d_out, int out_size, void* d_ws, size_t ws_size,
                              hipStream_t stream) {
  const float* x    = (const float*)d_in[0];
  const float* Wih0 = (const float*)d_in[1];
  const float* Whh0 = (const float*)d_in[2];
  const float* bih0 = (const float*)d_in[3];
  const float* bhh0 = (const float*)d_in[4];
  const float* Wih1 = (const float*)d_in[5];
  const float* Whh1 = (const float*)d_in[6];
  const float* bih1 = (const float*)d_in[7];
  const float* bhh1 = (const float*)d_in[8];
  const float* fcw  = (const float*)d_in[9];
  const float* fcb  = (const float*)d_in[10];
  float* out = (float*)d_out;

  hipLaunchKernelGGL(lstm2_pipe3, dim3(64), dim3(512), 0, stream,
                     x, Wih0, Whh0, bih0, bhh0, Wih1, Whh1, bih1, bhh1, fcw, fcb, out);
}

// Round 4
// 626.723 us; speedup vs baseline: 1.2941x; 1.2941x over previous
//
#include <hip/hip_runtime.h>
#include <hip/hip_bf16.h>

using short8  = __attribute__((ext_vector_type(8))) short;
using float4v = __attribute__((ext_vector_type(4))) float;
using uint4v  = __attribute__((ext_vector_type(4))) unsigned int;
using u32 = unsigned int;
using u16 = unsigned short;

#define MFMA(a,b,cc) __builtin_amdgcn_mfma_f32_16x16x32_bf16((a),(b),(cc),0,0,0)
// barrier draining only LDS ops: global prefetch stays in flight across it
#define PIPE_BARRIER() asm volatile("s_waitcnt lgkmcnt(0)\n\ts_barrier" ::: "memory")
#define LOG2E 1.44269504088896340736f

static __device__ __forceinline__ float fexp2(float x){ return __builtin_amdgcn_exp2f(x); }
static __device__ __forceinline__ float frcp(float x){ return __builtin_amdgcn_rcpf(x); }

static __device__ __forceinline__ short f2bf(float f){
  __hip_bfloat16 h = __float2bfloat16(f);
  return __builtin_bit_cast(short, h);
}
static __device__ __forceinline__ short8 load_bf8(const float* p){
  short8 v;
#pragma unroll
  for (int j = 0; j < 8; ++j) v[j] = f2bf(p[j]);
  return v;
}

// gate math, all lanes valid (lane owns one unit x 4 batch rows, 4 gate accs)
static __device__ __forceinline__ void gate4(const float4v& ai, const float4v& af,
                                             const float4v& ag, const float4v& ao,
                                             float (&cst)[4], float (&hv)[4]){
#pragma unroll
  for (int r = 0; r < 4; ++r){
    float iv = frcp(1.f + fexp2(-LOG2E * ai[r]));
    float fv = frcp(1.f + fexp2(-LOG2E * af[r]));
    float ov = frcp(1.f + fexp2(-LOG2E * ao[r]));
    float gv = 1.f - 2.f * frcp(1.f + fexp2((2.f*LOG2E) * ag[r]));
    float cn = fv * cst[r] + iv * gv;
    cst[r] = cn;
    float tc = 1.f - 2.f * frcp(1.f + fexp2((2.f*LOG2E) * cn));
    hv[r] = ov * tc;
  }
}

// =====================================================================
// Kernel 1: xg = bf16(x @ Wih0^T) in recurrent-fragment layout.
// Block: 16 batch x 8 t, 512 threads. Wave (th,wl): t = lt0+th*4+q, 4 gate tiles.
// xg dword index: (((lt*64 + bblk)*4 + wl)*64 + lane)*8 + d
//   d = gt*2 + (r>>1); lo half = r even, hi half = r odd.
// =====================================================================
__global__ __launch_bounds__(512) void xg_gemm(
    const float* __restrict__ x, const float* __restrict__ W,
    u32* __restrict__ xg, int tb)
{
  const int tid = threadIdx.x, lane = tid & 63, wv = tid >> 6;
  const int th = wv >> 2, wl = wv & 3;
  const int c = lane & 15, kg = lane >> 4;
  const int bblk = blockIdx.y;
  const int lt0  = blockIdx.x * 8;

  __shared__ __align__(16) float xs[8][16][136];

  { // stage x: 8 t x 16 b x 128 f32 = 64KB
    const int tt = tid >> 6;
    const int b  = (tid >> 2) & 15;
    const int off= (tid & 3) * 32;
    const float* g = x + ((size_t)(bblk*16 + b)*512 + (size_t)(tb + lt0 + tt))*128 + off;
    float4v* dst = (float4v*)&xs[tt][b][off];
#pragma unroll
    for (int q = 0; q < 8; ++q) dst[q] = *(const float4v*)(g + q*4);
  }

  // B fragments (Wih0), 16 frags
  short8 wb_[4][4];
#pragma unroll
  for (int gt = 0; gt < 4; ++gt){
    const int row = gt*64 + wl*16 + c;
#pragma unroll
    for (int kk = 0; kk < 4; ++kk)
      wb_[gt][kk] = load_bf8(W + row*128 + kk*32 + kg*8);
  }
  __syncthreads();

#pragma unroll
  for (int q = 0; q < 4; ++q){
    const int lt = lt0 + th*4 + q;
    short8 xb[4];
#pragma unroll
    for (int kk = 0; kk < 4; ++kk){
      const float* p = &xs[th*4 + q][c][kk*32 + kg*8];
      float4v v0 = *(const float4v*)p, v1 = *(const float4v*)(p + 4);
#pragma unroll
      for (int j = 0; j < 4; ++j){ xb[kk][j] = f2bf(v0[j]); xb[kk][4+j] = f2bf(v1[j]); }
    }
    float4v acc[4];
#pragma unroll
    for (int gt = 0; gt < 4; ++gt) acc[gt] = (float4v){0.f,0.f,0.f,0.f};
#pragma unroll
    for (int kk = 0; kk < 4; ++kk){
      acc[0] = MFMA(xb[kk], wb_[0][kk], acc[0]);
      acc[1] = MFMA(xb[kk], wb_[1][kk], acc[1]);
      acc[2] = MFMA(xb[kk], wb_[2][kk], acc[2]);
      acc[3] = MFMA(xb[kk], wb_[3][kk], acc[3]);
    }
    u32 dw[8];
#pragma unroll
    for (int d = 0; d < 8; ++d){
      const int gt = d >> 1, r0 = (d & 1) * 2;
      u32 lo = (u16)f2bf(acc[gt][r0]);
      u32 hi = (u16)f2bf(acc[gt][r0+1]);
      dw[d] = lo | (hi << 16);
    }
    u32* dst = xg + ((((size_t)lt*64 + bblk)*4 + wl)*64 + lane)*8;
    uint4v a = {dw[0],dw[1],dw[2],dw[3]};
    uint4v b4 = {dw[4],dw[5],dw[6],dw[7]};
    *(uint4v*)dst = a;
    *(uint4v*)(dst + 4) = b4;
  }
}

// =====================================================================
// Kernel 2: recurrent. Waves 0-3 layer0 (xg + h0 @ Whh0^T), waves 4-7 layer1,
// skewed by 1 step; 1 lgkm-only barrier per step.
// =====================================================================
static constexpr int XG_TSTRIDE = 64*4*64*8;   // dwords per t

template<int TPAR>
static __device__ __forceinline__ void l0_step(
    int lt, int nt, const u32* xgw, uint4v (&xc)[2],
    const short8 (&wh)[4][2], const float (&bs)[4],
    float (&cst)[4], __hip_bfloat16 (&h0s)[2][16][72],
    int c, int kg, int wl)
{
  short8 hf0 = *(const short8*)&h0s[TPAR^1][c][kg*8];
  short8 hf1 = *(const short8*)&h0s[TPAR^1][c][32 + kg*8];
  // acc init: unpack xg (bf16 pairs) + bias
  float4v av[4];
#pragma unroll
  for (int gt = 0; gt < 4; ++gt){
#pragma unroll
    for (int r = 0; r < 4; ++r){
      const int d = gt*2 + (r >> 1);
      u32 dw = (d < 4) ? xc[0][d] : xc[1][d-4];
      u32 bits = (r & 1) ? (dw & 0xffff0000u) : (dw << 16);
      av[gt][r] = __builtin_bit_cast(float, bits) + bs[gt];
    }
  }
  // prefetch xg for lt+2 (stays in flight across 2 barriers)
  if (lt + 2 < nt){
    const u32* p = xgw + (size_t)(lt + 2) * XG_TSTRIDE;
    xc[0] = *(const uint4v*)p;
    xc[1] = *(const uint4v*)(p + 4);
  }
  av[0] = MFMA(hf0, wh[0][0], av[0]); av[1] = MFMA(hf0, wh[1][0], av[1]);
  av[2] = MFMA(hf0, wh[2][0], av[2]); av[3] = MFMA(hf0, wh[3][0], av[3]);
  av[0] = MFMA(hf1, wh[0][1], av[0]); av[1] = MFMA(hf1, wh[1][1], av[1]);
  av[2] = MFMA(hf1, wh[2][1], av[2]); av[3] = MFMA(hf1, wh[3][1], av[3]);
  float hv[4];
  gate4(av[0], av[1], av[2], av[3], cst, hv);
#pragma unroll
  for (int r = 0; r < 4; ++r)
    h0s[TPAR][kg*4 + r][wl*16 + c] = __float2bfloat16(hv[r]);
}

template<int TPAR>
static __device__ __forceinline__ void l1_step(bool last,
    const short8 (&wi)[4][2], const short8 (&wh)[4][2], const float (&bs)[4],
    float (&cst)[4],
    const __hip_bfloat16 (&h0s)[2][16][72], __hip_bfloat16 (&h1s)[2][16][72],
    float (*hfin)[64], int c, int kg, int wl)
{
  short8 a0 = *(const short8*)&h0s[TPAR][c][kg*8];
  short8 a1 = *(const short8*)&h0s[TPAR][c][32 + kg*8];
  short8 b0 = *(const short8*)&h1s[TPAR^1][c][kg*8];
  short8 b1 = *(const short8*)&h1s[TPAR^1][c][32 + kg*8];
  float4v av[4];
#pragma unroll
  for (int gt = 0; gt < 4; ++gt) av[gt] = (float4v){bs[gt],bs[gt],bs[gt],bs[gt]};
  av[0] = MFMA(a0, wi[0][0], av[0]); av[1] = MFMA(a0, wi[1][0], av[1]);
  av[2] = MFMA(a0, wi[2][0], av[2]); av[3] = MFMA(a0, wi[3][0], av[3]);
  av[0] = MFMA(a1, wi[0][1], av[0]); av[1] = MFMA(a1, wi[1][1], av[1]);
  av[2] = MFMA(a1, wi[2][1], av[2]); av[3] = MFMA(a1, wi[3][1], av[3]);
  av[0] = MFMA(b0, wh[0][0], av[0]); av[1] = MFMA(b0, wh[1][0], av[1]);
  av[2] = MFMA(b0, wh[2][0], av[2]); av[3] = MFMA(b0, wh[3][0], av[3]);
  av[0] = MFMA(b1, wh[0][1], av[0]); av[1] = MFMA(b1, wh[1][1], av[1]);
  av[2] = MFMA(b1, wh[2][1], av[2]); av[3] = MFMA(b1, wh[3][1], av[3]);
  float hv[4];
  gate4(av[0], av[1], av[2], av[3], cst, hv);
#pragma unroll
  for (int r = 0; r < 4; ++r){
    h1s[TPAR][kg*4 + r][wl*16 + c] = __float2bfloat16(hv[r]);
    if (last) hfin[kg*4 + r][wl*16 + c] = hv[r];
  }
}

__global__ __launch_bounds__(512, 2) void lstm_rec(
    const u32* __restrict__ xg,
    const float* __restrict__ Whh0, const float* __restrict__ bih0, const float* __restrict__ bhh0,
    const float* __restrict__ Wih1, const float* __restrict__ Whh1,
    const float* __restrict__ bih1, const float* __restrict__ bhh1,
    const float* __restrict__ fcw,  const float* __restrict__ fcb,
    float* __restrict__ out,
    float* __restrict__ cstate, u16* __restrict__ h0st, u16* __restrict__ h1st,
    int tb, int nt)
{
  const int tid  = threadIdx.x;
  const int lane = tid & 63;
  const int wv   = tid >> 6;
  const int grp  = wv >> 2;
  const int wl   = wv & 3;
  const int c    = lane & 15;
  const int kg   = lane >> 4;
  const int bblk = blockIdx.x;

  __shared__ __align__(16) __hip_bfloat16 h0s[2][16][72];
  __shared__ __align__(16) __hip_bfloat16 h1s[2][16][72];
  __shared__ float hfin[16][64];

  float cst[4];
  if (tb == 0){
    __hip_bfloat16 z = __float2bfloat16(0.f);
    for (int i = tid; i < 2*16*72; i += 512){
      (&h0s[0][0][0])[i] = z;
      (&h1s[0][0][0])[i] = z;
    }
#pragma unroll
    for (int r = 0; r < 4; ++r) cst[r] = 0.f;
  } else {
    for (int i = tid; i < 1024; i += 512){
      ((u16*)&h0s[1][0][0])[(i>>6)*72 + (i&63)] = h0st[bblk*1024 + i];
      ((u16*)&h1s[0][0][0])[(i>>6)*72 + (i&63)] = h1st[bblk*1024 + i];
    }
#pragma unroll
    for (int r = 0; r < 4; ++r) cst[r] = cstate[((size_t)bblk*512 + tid)*4 + r];
  }

  // weights (resident; total live regs ~120 so no remat pressure)
  short8 wi[4][2], wh[4][2];
  float  bs[4];
  const int urow = wl*16 + c;
  if (grp == 0){
#pragma unroll
    for (int gt = 0; gt < 4; ++gt){
      const int row = gt*64 + urow;
#pragma unroll
      for (int kk = 0; kk < 2; ++kk)
        wh[gt][kk] = load_bf8(Whh0 + row*64 + kk*32 + kg*8);
      bs[gt] = bih0[row] + bhh0[row];
    }
  } else {
#pragma unroll
    for (int gt = 0; gt < 4; ++gt){
      const int row = gt*64 + urow;
#pragma unroll
      for (int kk = 0; kk < 2; ++kk){
        wi[gt][kk] = load_bf8(Wih1 + row*64 + kk*32 + kg*8);
        wh[gt][kk] = load_bf8(Whh1 + row*64 + kk*32 + kg*8);
      }
      bs[gt] = bih1[row] + bhh1[row];
    }
  }

  // xg prefetch buffers (grp0)
  const u32* xgw = nullptr;
  uint4v xcA[2], xcB[2];
  if (grp == 0){
    xgw = xg + (((size_t)bblk*4 + wl)*64 + lane)*8;
    xcA[0] = *(const uint4v*)xgw;               xcA[1] = *(const uint4v*)(xgw + 4);
    const u32* p1 = xgw + XG_TSTRIDE;
    xcB[0] = *(const uint4v*)p1;                xcB[1] = *(const uint4v*)(p1 + 4);
  }

  __syncthreads();

  for (int lt = 0; lt < nt; lt += 2){
    // window A: L0 local t=lt (even parity), L1 t1 = tb+lt-1 (odd parity)
    if (grp == 0) l0_step<0>(lt, nt, xgw, xcA, wh, bs, cst, h0s, c, kg, wl);
    else if (tb + lt > 0) l1_step<1>(false, wi, wh, bs, cst, h0s, h1s, hfin, c, kg, wl);
    PIPE_BARRIER();
    // window B: L0 t=lt+1 (odd), L1 t1 = tb+lt (even)
    if (grp == 0) l0_step<1>(lt+1, nt, xgw, xcB, wh, bs, cst, h0s, c, kg, wl);
    else          l1_step<0>(false, wi, wh, bs, cst, h0s, h1s, hfin, c, kg, wl);
    PIPE_BARRIER();
  }
  // epilogue only on last chunk: t1 = 511 (odd parity)
  if (grp == 1 && tb + nt == 512)
    l1_step<1>(true, wi, wh, bs, cst, h0s, h1s, hfin, c, kg, wl);
  __syncthreads();

  if (tb + nt < 512){
    for (int i = tid; i < 1024; i += 512){
      h0st[bblk*1024 + i] = ((const u16*)&h0s[1][0][0])[(i>>6)*72 + (i&63)];
      h1st[bblk*1024 + i] = ((const u16*)&h1s[0][0][0])[(i>>6)*72 + (i&63)];
    }
#pragma unroll
    for (int r = 0; r < 4; ++r) cstate[((size_t)bblk*512 + tid)*4 + r] = cst[r];
  } else if (tid < 16){
    float s = fcb[0];
#pragma unroll
    for (int k = 0; k < 64; ++k) s += hfin[tid][k] * fcw[k];
    out[(bblk << 4) + tid] = frcp(1.f + fexp2(-LOG2E * s));
  }
}

extern "C" void kernel_launch(void* const* d_in, const int* in_sizes, int n_in,
                              void* d_out, int out_size, void* d_ws, size_t ws_size,
                              hipStream_t stream) {
  const float* x    = (const float*)d_in[0];
  const float* Wih0 = (const float*)d_in[1];
  const float* Whh0 = (const float*)d_in[2];
  const float* bih0 = (const float*)d_in[3];
  const float* bhh0 = (const float*)d_in[4];
  const float* Wih1 = (const float*)d_in[5];
  const float* Whh1 = (const float*)d_in[6];
  const float* bih1 = (const float*)d_in[7];
  const float* bhh1 = (const float*)d_in[8];
  const float* fcw  = (const float*)d_in[9];
  const float* fcb  = (const float*)d_in[10];
  float* out = (float*)d_out;

  // chunk length CT: xg needs CT*512KB, state needs <1MB
  const size_t perT = 1024ull * 256 * 2;   // 512 KB per t
  int CT = 512;
  while (CT > 8 && (size_t)CT * perT + (1u << 20) > ws_size) CT >>= 1;

  u32* xg = (u32*)d_ws;
  char* sb = (char*)d_ws + (size_t)CT * perT;
  float* cstate = (float*)sb;                       // 512 KB
  u16*   h0st   = (u16*)(sb + (512u << 10));        // 128 KB
  u16*   h1st   = (u16*)(sb + (512u << 10) + (128u << 10));

  for (int tb = 0; tb < 512; tb += CT){
    hipLaunchKernelGGL(xg_gemm, dim3(CT/8, 64), dim3(512), 0, stream,
                       x, Wih0, xg, tb);
    hipLaunchKernelGGL(lstm_rec, dim3(64), dim3(512), 0, stream,
                       xg, Whh0, bih0, bhh0, Wih1, Whh1, bih1, bhh1,
                       fcw, fcb, out, cstate, h0st, h1st, tb, CT);
  }
}

// Round 5
// 612.393 us; speedup vs baseline: 1.3244x; 1.0234x over previous
//
#include <hip/hip_runtime.h>
#include <hip/hip_bf16.h>

using short8  = __attribute__((ext_vector_type(8))) short;
using float4v = __attribute__((ext_vector_type(4))) float;
using uint4v  = __attribute__((ext_vector_type(4))) unsigned int;
using u32 = unsigned int;
using u16 = unsigned short;

#define MFMA(a,b,cc) __builtin_amdgcn_mfma_f32_16x16x32_bf16((a),(b),(cc),0,0,0)
// barrier draining only LDS ops: global prefetch stays in flight across it
#define PIPE_BARRIER() asm volatile("s_waitcnt lgkmcnt(0)\n\ts_barrier" ::: "memory")
#define LOG2E 1.44269504088896340736f

static __device__ __forceinline__ float fexp2(float x){ return __builtin_amdgcn_exp2f(x); }
static __device__ __forceinline__ float frcp(float x){ return __builtin_amdgcn_rcpf(x); }

static __device__ __forceinline__ short f2bf(float f){
  __hip_bfloat16 h = __float2bfloat16(f);
  return __builtin_bit_cast(short, h);
}
static __device__ __forceinline__ short8 load_bf8(const float* p){
  short8 v;
#pragma unroll
  for (int j = 0; j < 8; ++j) v[j] = f2bf(p[j]);
  return v;
}

// gate math, all lanes valid (lane owns one unit x 4 batch rows, 4 gate accs)
static __device__ __forceinline__ void gate4(const float4v& ai, const float4v& af,
                                             const float4v& ag, const float4v& ao,
                                             float (&cst)[4], float (&hv)[4]){
#pragma unroll
  for (int r = 0; r < 4; ++r){
    float iv = frcp(1.f + fexp2(-LOG2E * ai[r]));
    float fv = frcp(1.f + fexp2(-LOG2E * af[r]));
    float ov = frcp(1.f + fexp2(-LOG2E * ao[r]));
    float gv = 1.f - 2.f * frcp(1.f + fexp2((2.f*LOG2E) * ag[r]));
    float cn = fv * cst[r] + iv * gv;
    cst[r] = cn;
    float tc = 1.f - 2.f * frcp(1.f + fexp2((2.f*LOG2E) * cn));
    hv[r] = ov * tc;
  }
}

// =====================================================================
// Kernel 1: xg = bf16(x @ Wih0^T) in recurrent-fragment layout.
// xg dword index: (((lt*64 + bblk)*4 + wl)*64 + lane)*8 + d
//   d = gt*2 + (r>>1); lo half = r even, hi half = r odd.
// =====================================================================
__global__ __launch_bounds__(512) void xg_gemm(
    const float* __restrict__ x, const float* __restrict__ W,
    u32* __restrict__ xg, int tb)
{
  const int tid = threadIdx.x, lane = tid & 63, wv = tid >> 6;
  const int th = wv >> 2, wl = wv & 3;
  const int c = lane & 15, kg = lane >> 4;
  const int bblk = blockIdx.y;
  const int lt0  = blockIdx.x * 8;

  __shared__ __align__(16) float xs[8][16][136];

  { // stage x: 8 t x 16 b x 128 f32 = 64KB
    const int tt = tid >> 6;
    const int b  = (tid >> 2) & 15;
    const int off= (tid & 3) * 32;
    const float* g = x + ((size_t)(bblk*16 + b)*512 + (size_t)(tb + lt0 + tt))*128 + off;
    float4v* dst = (float4v*)&xs[tt][b][off];
#pragma unroll
    for (int q = 0; q < 8; ++q) dst[q] = *(const float4v*)(g + q*4);
  }

  short8 wb_[4][4];
#pragma unroll
  for (int gt = 0; gt < 4; ++gt){
    const int row = gt*64 + wl*16 + c;
#pragma unroll
    for (int kk = 0; kk < 4; ++kk)
      wb_[gt][kk] = load_bf8(W + row*128 + kk*32 + kg*8);
  }
  __syncthreads();

#pragma unroll
  for (int q = 0; q < 4; ++q){
    const int lt = lt0 + th*4 + q;
    short8 xb[4];
#pragma unroll
    for (int kk = 0; kk < 4; ++kk){
      const float* p = &xs[th*4 + q][c][kk*32 + kg*8];
      float4v v0 = *(const float4v*)p, v1 = *(const float4v*)(p + 4);
#pragma unroll
      for (int j = 0; j < 4; ++j){ xb[kk][j] = f2bf(v0[j]); xb[kk][4+j] = f2bf(v1[j]); }
    }
    float4v acc[4];
#pragma unroll
    for (int gt = 0; gt < 4; ++gt) acc[gt] = (float4v){0.f,0.f,0.f,0.f};
#pragma unroll
    for (int kk = 0; kk < 4; ++kk){
      acc[0] = MFMA(xb[kk], wb_[0][kk], acc[0]);
      acc[1] = MFMA(xb[kk], wb_[1][kk], acc[1]);
      acc[2] = MFMA(xb[kk], wb_[2][kk], acc[2]);
      acc[3] = MFMA(xb[kk], wb_[3][kk], acc[3]);
    }
    u32 dw[8];
#pragma unroll
    for (int d = 0; d < 8; ++d){
      const int gt = d >> 1, r0 = (d & 1) * 2;
      u32 lo = (u16)f2bf(acc[gt][r0]);
      u32 hi = (u16)f2bf(acc[gt][r0+1]);
      dw[d] = lo | (hi << 16);
    }
    u32* dst = xg + ((((size_t)lt*64 + bblk)*4 + wl)*64 + lane)*8;
    uint4v a = {dw[0],dw[1],dw[2],dw[3]};
    uint4v b4 = {dw[4],dw[5],dw[6],dw[7]};
    *(uint4v*)dst = a;
    *(uint4v*)(dst + 4) = b4;
  }
}

// =====================================================================
// Kernel 2: recurrent. Waves 0-3 layer0 (xg + h0 @ Whh0^T), waves 4-7 layer1,
// skewed by 1 step; 1 lgkm-only barrier per step. xg register-prefetch depth 4,
// consumed AFTER the h-MFMAs so the vmem wait sits late in the window.
// =====================================================================
static constexpr int XG_TSTRIDE = 64*4*64*8;   // dwords per t

template<int OFF>
static __device__ __forceinline__ void l0_step(
    int lt, int nt, const u32* xgw, uint4v (&xc)[4][2],
    const short8 (&wh)[4][2], const float (&bs)[4],
    float (&cst)[4], __hip_bfloat16 (&h0s)[2][16][72],
    int c, int kg, int wl)
{
  constexpr int P  = OFF & 1;        // h0 parity of this step
  constexpr int CU = OFF;            // buffer consumed this step
  constexpr int FB = (OFF + 3) & 3;  // buffer filled for step lt+OFF+3
  short8 hf0 = *(const short8*)&h0s[P^1][c][kg*8];
  short8 hf1 = *(const short8*)&h0s[P^1][c][32 + kg*8];
  // issue prefetch early (3 windows of latency budget)
  {
    int tn = lt + OFF + 3; if (tn > nt - 1) tn = nt - 1;  // clamp: uniform flow
    const u32* p = xgw + (size_t)tn * XG_TSTRIDE;
    xc[FB][0] = *(const uint4v*)p;
    xc[FB][1] = *(const uint4v*)(p + 4);
  }
  float4v av[4];
#pragma unroll
  for (int gt = 0; gt < 4; ++gt) av[gt] = (float4v){bs[gt],bs[gt],bs[gt],bs[gt]};
  av[0] = MFMA(hf0, wh[0][0], av[0]); av[1] = MFMA(hf0, wh[1][0], av[1]);
  av[2] = MFMA(hf0, wh[2][0], av[2]); av[3] = MFMA(hf0, wh[3][0], av[3]);
  av[0] = MFMA(hf1, wh[0][1], av[0]); av[1] = MFMA(hf1, wh[1][1], av[1]);
  av[2] = MFMA(hf1, wh[2][1], av[2]); av[3] = MFMA(hf1, wh[3][1], av[3]);
  // consume xg (bf16 pairs) — vmem wait lands here, not at window top
#pragma unroll
  for (int gt = 0; gt < 4; ++gt){
#pragma unroll
    for (int r = 0; r < 4; ++r){
      const int d = gt*2 + (r >> 1);
      u32 dw = (d < 4) ? xc[CU][0][d] : xc[CU][1][d-4];
      u32 bits = (r & 1) ? (dw & 0xffff0000u) : (dw << 16);
      av[gt][r] += __builtin_bit_cast(float, bits);
    }
  }
  float hv[4];
  gate4(av[0], av[1], av[2], av[3], cst, hv);
#pragma unroll
  for (int r = 0; r < 4; ++r)
    h0s[P][kg*4 + r][wl*16 + c] = __float2bfloat16(hv[r]);
}

template<int TPAR>
static __device__ __forceinline__ void l1_step(bool last,
    const short8 (&wi)[4][2], const short8 (&wh)[4][2], const float (&bs)[4],
    float (&cst)[4],
    const __hip_bfloat16 (&h0s)[2][16][72], __hip_bfloat16 (&h1s)[2][16][72],
    float (*hfin)[64], int c, int kg, int wl)
{
  short8 a0 = *(const short8*)&h0s[TPAR][c][kg*8];
  short8 a1 = *(const short8*)&h0s[TPAR][c][32 + kg*8];
  short8 b0 = *(const short8*)&h1s[TPAR^1][c][kg*8];
  short8 b1 = *(const short8*)&h1s[TPAR^1][c][32 + kg*8];
  float4v av[4];
#pragma unroll
  for (int gt = 0; gt < 4; ++gt) av[gt] = (float4v){bs[gt],bs[gt],bs[gt],bs[gt]};
  av[0] = MFMA(a0, wi[0][0], av[0]); av[1] = MFMA(a0, wi[1][0], av[1]);
  av[2] = MFMA(a0, wi[2][0], av[2]); av[3] = MFMA(a0, wi[3][0], av[3]);
  av[0] = MFMA(a1, wi[0][1], av[0]); av[1] = MFMA(a1, wi[1][1], av[1]);
  av[2] = MFMA(a1, wi[2][1], av[2]); av[3] = MFMA(a1, wi[3][1], av[3]);
  av[0] = MFMA(b0, wh[0][0], av[0]); av[1] = MFMA(b0, wh[1][0], av[1]);
  av[2] = MFMA(b0, wh[2][0], av[2]); av[3] = MFMA(b0, wh[3][0], av[3]);
  av[0] = MFMA(b1, wh[0][1], av[0]); av[1] = MFMA(b1, wh[1][1], av[1]);
  av[2] = MFMA(b1, wh[2][1], av[2]); av[3] = MFMA(b1, wh[3][1], av[3]);
  float hv[4];
  gate4(av[0], av[1], av[2], av[3], cst, hv);
#pragma unroll
  for (int r = 0; r < 4; ++r){
    h1s[TPAR][kg*4 + r][wl*16 + c] = __float2bfloat16(hv[r]);
    if (last) hfin[kg*4 + r][wl*16 + c] = hv[r];
  }
}

__global__ __launch_bounds__(512, 1) void lstm_rec(
    const u32* __restrict__ xg,
    const float* __restrict__ Whh0, const float* __restrict__ bih0, const float* __restrict__ bhh0,
    const float* __restrict__ Wih1, const float* __restrict__ Whh1,
    const float* __restrict__ bih1, const float* __restrict__ bhh1,
    const float* __restrict__ fcw,  const float* __restrict__ fcb,
    float* __restrict__ out,
    float* __restrict__ cstate, u16* __restrict__ h0st, u16* __restrict__ h1st,
    int tb, int nt)
{
  const int tid  = threadIdx.x;
  const int lane = tid & 63;
  const int wv   = tid >> 6;
  const int grp  = wv >> 2;
  const int wl   = wv & 3;
  const int c    = lane & 15;
  const int kg   = lane >> 4;
  const int bblk = blockIdx.x;

  __shared__ __align__(16) __hip_bfloat16 h0s[2][16][72];
  __shared__ __align__(16) __hip_bfloat16 h1s[2][16][72];
  __shared__ float hfin[16][64];

  float cst[4];
  if (tb == 0){
    __hip_bfloat16 z = __float2bfloat16(0.f);
    for (int i = tid; i < 2*16*72; i += 512){
      (&h0s[0][0][0])[i] = z;
      (&h1s[0][0][0])[i] = z;
    }
#pragma unroll
    for (int r = 0; r < 4; ++r) cst[r] = 0.f;
  } else {
    for (int i = tid; i < 1024; i += 512){
      ((u16*)&h0s[1][0][0])[(i>>6)*72 + (i&63)] = h0st[bblk*1024 + i];
      ((u16*)&h1s[0][0][0])[(i>>6)*72 + (i&63)] = h1st[bblk*1024 + i];
    }
#pragma unroll
    for (int r = 0; r < 4; ++r) cst[r] = cstate[((size_t)bblk*512 + tid)*4 + r];
  }

  // weights: launch_bounds(512,1) lifts the reg cap so these stay resident
  short8 wi[4][2], wh[4][2];
  float  bs[4];
  const int urow = wl*16 + c;
  if (grp == 0){
#pragma unroll
    for (int gt = 0; gt < 4; ++gt){
      const int row = gt*64 + urow;
#pragma unroll
      for (int kk = 0; kk < 2; ++kk)
        wh[gt][kk] = load_bf8(Whh0 + row*64 + kk*32 + kg*8);
      bs[gt] = bih0[row] + bhh0[row];
    }
  } else {
#pragma unroll
    for (int gt = 0; gt < 4; ++gt){
      const int row = gt*64 + urow;
#pragma unroll
      for (int kk = 0; kk < 2; ++kk){
        wi[gt][kk] = load_bf8(Wih1 + row*64 + kk*32 + kg*8);
        wh[gt][kk] = load_bf8(Whh1 + row*64 + kk*32 + kg*8);
      }
      bs[gt] = bih1[row] + bhh1[row];
    }
  }

  // xg prefetch ring, depth 4 (static indices only)
  const u32* xgw = nullptr;
  uint4v xc[4][2];
  if (grp == 0){
    xgw = xg + (((size_t)bblk*4 + wl)*64 + lane)*8;
#pragma unroll
    for (int s = 0; s < 3; ++s){
      const u32* p = xgw + (size_t)s * XG_TSTRIDE;
      xc[s][0] = *(const uint4v*)p;
      xc[s][1] = *(const uint4v*)(p + 4);
    }
  }

  __syncthreads();

  for (int lt = 0; lt < nt; lt += 4){
    // OFF=0: L0 t=lt (P=0), L1 t1=tb+lt-1 (parity 1)
    if (grp == 0) l0_step<0>(lt, nt, xgw, xc, wh, bs, cst, h0s, c, kg, wl);
    else if (tb + lt > 0) l1_step<1>(false, wi, wh, bs, cst, h0s, h1s, hfin, c, kg, wl);
    PIPE_BARRIER();
    // OFF=1: L0 t=lt+1 (P=1), L1 t1=tb+lt (parity 0)
    if (grp == 0) l0_step<1>(lt, nt, xgw, xc, wh, bs, cst, h0s, c, kg, wl);
    else          l1_step<0>(false, wi, wh, bs, cst, h0s, h1s, hfin, c, kg, wl);
    PIPE_BARRIER();
    // OFF=2: L0 t=lt+2 (P=0), L1 t1=tb+lt+1 (parity 1)
    if (grp == 0) l0_step<2>(lt, nt, xgw, xc, wh, bs, cst, h0s, c, kg, wl);
    else          l1_step<1>(false, wi, wh, bs, cst, h0s, h1s, hfin, c, kg, wl);
    PIPE_BARRIER();
    // OFF=3: L0 t=lt+3 (P=1), L1 t1=tb+lt+2 (parity 0)
    if (grp == 0) l0_step<3>(lt, nt, xgw, xc, wh, bs, cst, h0s, c, kg, wl);
    else          l1_step<0>(false, wi, wh, bs, cst, h0s, h1s, hfin, c, kg, wl);
    PIPE_BARRIER();
  }
  // epilogue only on last chunk: t1 = 511 (odd parity)
  if (grp == 1 && tb + nt == 512)
    l1_step<1>(true, wi, wh, bs, cst, h0s, h1s, hfin, c, kg, wl);
  __syncthreads();

  if (tb + nt < 512){
    for (int i = tid; i < 1024; i += 512){
      h0st[bblk*1024 + i] = ((const u16*)&h0s[1][0][0])[(i>>6)*72 + (i&63)];
      h1st[bblk*1024 + i] = ((const u16*)&h1s[0][0][0])[(i>>6)*72 + (i&63)];
    }
#pragma unroll
    for (int r = 0; r < 4; ++r) cstate[((size_t)bblk*512 + tid)*4 + r] = cst[r];
  } else if (tid < 16){
    float s = fcb[0];
#pragma unroll
    for (int k = 0; k < 64; ++k) s += hfin[tid][k] * fcw[k];
    out[(bblk << 4) + tid] = frcp(1.f + fexp2(-LOG2E * s));
  }
}

extern "C" void kernel_launch(void* const* d_in, const int* in_sizes, int n_in,
                              void* d_out, int out_size, void* d_ws, size_t ws_size,
                              hipStream_t stream) {
  const float* x    = (const float*)d_in[0];
  const float* Wih0 = (const float*)d_in[1];
  const float* Whh0 = (const float*)d_in[2];
  const float* bih0 = (const float*)d_in[3];
  const float* bhh0 = (const float*)d_in[4];
  const float* Wih1 = (const float*)d_in[5];
  const float* Whh1 = (const float*)d_in[6];
  const float* bih1 = (const float*)d_in[7];
  const float* bhh1 = (const float*)d_in[8];
  const float* fcw  = (const float*)d_in[9];
  const float* fcb  = (const float*)d_in[10];
  float* out = (float*)d_out;

  const size_t perT = 1024ull * 256 * 2;   // 512 KB per t
  int CT = 512;
  while (CT > 8 && (size_t)CT * perT + (1u << 20) > ws_size) CT >>= 1;

  u32* xg = (u32*)d_ws;
  char* sb = (char*)d_ws + (size_t)CT * perT;
  float* cstate = (float*)sb;                       // 512 KB
  u16*   h0st   = (u16*)(sb + (512u << 10));        // 128 KB
  u16*   h1st   = (u16*)(sb + (512u << 10) + (128u << 10));

  for (int tb = 0; tb < 512; tb += CT){
    hipLaunchKernelGGL(xg_gemm, dim3(CT/8, 64), dim3(512), 0, stream,
                       x, Wih0, xg, tb);
    hipLaunchKernelGGL(lstm_rec, dim3(64), dim3(512), 0, stream,
                       xg, Whh0, bih0, bhh0, Wih1, Whh1, bih1, bhh1,
                       fcw, fcb, out, cstate, h0st, h1st, tb, CT);
  }
}

// Round 6
// 493.785 us; speedup vs baseline: 1.6426x; 1.2402x over previous
//
#include <hip/hip_runtime.h>
#include <hip/hip_bf16.h>

using short8  = __attribute__((ext_vector_type(8))) short;
using float4v = __attribute__((ext_vector_type(4))) float;
using uint2v  = __attribute__((ext_vector_type(2))) unsigned int;
using uint4v  = __attribute__((ext_vector_type(4))) unsigned int;
using u32 = unsigned int;
using u16 = unsigned short;

#define MFMA(a,b,cc) __builtin_amdgcn_mfma_f32_16x16x32_bf16((a),(b),(cc),0,0,0)
// barrier draining only LDS ops: global prefetch stays in flight across it
#define PIPE_BARRIER() asm volatile("s_waitcnt lgkmcnt(0)\n\ts_barrier" ::: "memory")
#define LOG2E 1.44269504088896340736f

static __device__ __forceinline__ float fexp2(float x){ return __builtin_amdgcn_exp2f(x); }
static __device__ __forceinline__ float frcp(float x){ return __builtin_amdgcn_rcpf(x); }

static __device__ __forceinline__ short f2bf(float f){
  __hip_bfloat16 h = __float2bfloat16(f);
  return __builtin_bit_cast(short, h);
}
static __device__ __forceinline__ short8 load_bf8(const float* p){
  short8 v;
#pragma unroll
  for (int j = 0; j < 8; ++j) v[j] = f2bf(p[j]);
  return v;
}
static __device__ __forceinline__ float bflo(u32 d){ return __builtin_bit_cast(float, d << 16); }
static __device__ __forceinline__ float bfhi(u32 d){ return __builtin_bit_cast(float, d & 0xffff0000u); }

// single-cell gate math: 10 trans
static __device__ __forceinline__ float gates1(float ai, float af, float ag, float ao, float& cst){
  float iv = frcp(1.f + fexp2(-LOG2E * ai));
  float fv = frcp(1.f + fexp2(-LOG2E * af));
  float ov = frcp(1.f + fexp2(-LOG2E * ao));
  float gv = 1.f - 2.f * frcp(1.f + fexp2((2.f*LOG2E) * ag));
  float cn = fv * cst + iv * gv;
  cst = cn;
  float tc = 1.f - 2.f * frcp(1.f + fexp2((2.f*LOG2E) * cn));
  return ov * tc;
}

// =====================================================================
// Kernel 1: xg = bf16(x @ Wih0^T), laid out for the 4-row rec blocks:
// dword index = ((lt*256 + rb)*256 + wl*64 + b4*16 + c)*2  (+0: i|f, +1: g|o)
//   rb = global batch row / 4, b4 = row % 4, u = wl*16 + c.
// =====================================================================
__global__ __launch_bounds__(512) void xg_gemm(
    const float* __restrict__ x, const float* __restrict__ W,
    u32* __restrict__ xg, int tb)
{
  const int tid = threadIdx.x, lane = tid & 63, wv = tid >> 6;
  const int th = wv >> 2, wl = wv & 3;
  const int c = lane & 15, kg = lane >> 4;
  const int bblk = blockIdx.y;          // 16-batch block
  const int lt0  = blockIdx.x * 8;

  __shared__ __align__(16) float xs[8][16][136];

  { // stage x: 8 t x 16 b x 128 f32 = 64KB
    const int tt = tid >> 6;
    const int b  = (tid >> 2) & 15;
    const int off= (tid & 3) * 32;
    const float* g = x + ((size_t)(bblk*16 + b)*512 + (size_t)(tb + lt0 + tt))*128 + off;
    float4v* dst = (float4v*)&xs[tt][b][off];
#pragma unroll
    for (int q = 0; q < 8; ++q) dst[q] = *(const float4v*)(g + q*4);
  }

  short8 wb_[4][4];
#pragma unroll
  for (int gt = 0; gt < 4; ++gt){
    const int row = gt*64 + wl*16 + c;
#pragma unroll
    for (int kk = 0; kk < 4; ++kk)
      wb_[gt][kk] = load_bf8(W + row*128 + kk*32 + kg*8);
  }
  __syncthreads();

#pragma unroll
  for (int q = 0; q < 4; ++q){
    const int lt = lt0 + th*4 + q;
    short8 xb[4];
#pragma unroll
    for (int kk = 0; kk < 4; ++kk){
      const float* p = &xs[th*4 + q][c][kk*32 + kg*8];
      float4v v0 = *(const float4v*)p, v1 = *(const float4v*)(p + 4);
#pragma unroll
      for (int j = 0; j < 4; ++j){ xb[kk][j] = f2bf(v0[j]); xb[kk][4+j] = f2bf(v1[j]); }
    }
    float4v acc[4];
#pragma unroll
    for (int gt = 0; gt < 4; ++gt) acc[gt] = (float4v){0.f,0.f,0.f,0.f};
#pragma unroll
    for (int kk = 0; kk < 4; ++kk){
      acc[0] = MFMA(xb[kk], wb_[0][kk], acc[0]);
      acc[1] = MFMA(xb[kk], wb_[1][kk], acc[1]);
      acc[2] = MFMA(xb[kk], wb_[2][kk], acc[2]);
      acc[3] = MFMA(xb[kk], wb_[3][kk], acc[3]);
    }
    // store: acc row = kg*4 + r -> rec block rb = bblk*4 + kg, b4 = r
    u32* base = xg + (((size_t)lt*256 + (size_t)bblk*4 + kg)*256 + wl*64 + c)*2;
#pragma unroll
    for (int r = 0; r < 4; ++r){
      u32 d0 = (u32)(u16)f2bf(acc[0][r]) | ((u32)(u16)f2bf(acc[1][r]) << 16);
      u32 d1 = (u32)(u16)f2bf(acc[2][r]) | ((u32)(u16)f2bf(acc[3][r]) << 16);
      uint2v dv = {d0, d1};
      *(uint2v*)(base + r*32) = dv;
    }
  }
}

// =====================================================================
// Kernel 2: recurrent, 256 blocks x 4 batch rows, 8 waves.
// Waves 0-3: layer0 unit-tile wl; waves 4-7: layer1 tile wl, skew 1 step.
// MFMA valid rows 0-3 live in lanes 0-15; LDS tmp redistributes to
// 1 cell/lane (lane l -> batch kg=l>>4, unit wl*16 + (l&15)).
// =====================================================================
static constexpr int XG_TSTRIDE = 256*256*2;   // dwords per t

template<int OFF>
static __device__ __forceinline__ void l0_step(
    int lt, int nt, const u32* xgw, uint2v (&xc)[4],
    const short8 (&wh)[4][2], const float (&bs)[4],
    float& cst, __hip_bfloat16 (&h0s)[2][16][72],
    float (*tp)[20], int lane, int c, int kg, int wl)
{
  constexpr int P  = OFF & 1;
  constexpr int CU = OFF;
  constexpr int FB = (OFF + 3) & 3;
  short8 hf0 = *(const short8*)&h0s[P^1][c][kg*8];
  short8 hf1 = *(const short8*)&h0s[P^1][c][32 + kg*8];
  { // prefetch xg for step lt+OFF+3
    int tn = lt + OFF + 3; if (tn > nt - 1) tn = nt - 1;
    xc[FB] = *(const uint2v*)(xgw + (size_t)tn * XG_TSTRIDE);
  }
  float4v av[4];
#pragma unroll
  for (int gt = 0; gt < 4; ++gt) av[gt] = (float4v){0.f,0.f,0.f,0.f};
  av[0] = MFMA(hf0, wh[0][0], av[0]); av[1] = MFMA(hf0, wh[1][0], av[1]);
  av[2] = MFMA(hf0, wh[2][0], av[2]); av[3] = MFMA(hf0, wh[3][0], av[3]);
  av[0] = MFMA(hf1, wh[0][1], av[0]); av[1] = MFMA(hf1, wh[1][1], av[1]);
  av[2] = MFMA(hf1, wh[2][1], av[2]); av[3] = MFMA(hf1, wh[3][1], av[3]);
  // redistribute: lanes 0-15 (rows 0-3 valid) -> 1 cell/lane
  if (lane < 16){
#pragma unroll
    for (int r = 0; r < 4; ++r){
      float4v t_ = {av[0][r], av[1][r], av[2][r], av[3][r]};
      *(float4v*)&tp[lane][r*4] = t_;
    }
  }
  float4v g4 = *(const float4v*)&tp[c][kg*4];
  u32 d0 = xc[CU][0], d1 = xc[CU][1];
  float ai = g4[0] + bs[0] + bflo(d0);
  float af = g4[1] + bs[1] + bfhi(d0);
  float ag = g4[2] + bs[2] + bflo(d1);
  float ao = g4[3] + bs[3] + bfhi(d1);
  float hv = gates1(ai, af, ag, ao, cst);
  h0s[P][kg][wl*16 + c] = __float2bfloat16(hv);
}

template<int TPAR>
static __device__ __forceinline__ void l1_step(bool last,
    const short8 (&wi)[4][2], const short8 (&wh)[4][2], const float (&bs)[4],
    float& cst,
    const __hip_bfloat16 (&h0s)[2][16][72], __hip_bfloat16 (&h1s)[2][16][72],
    float (*tp)[20], float (*hfin)[64], int lane, int c, int kg, int wl)
{
  short8 a0 = *(const short8*)&h0s[TPAR][c][kg*8];
  short8 a1 = *(const short8*)&h0s[TPAR][c][32 + kg*8];
  short8 b0 = *(const short8*)&h1s[TPAR^1][c][kg*8];
  short8 b1 = *(const short8*)&h1s[TPAR^1][c][32 + kg*8];
  float4v av[4];
#pragma unroll
  for (int gt = 0; gt < 4; ++gt) av[gt] = (float4v){0.f,0.f,0.f,0.f};
  av[0] = MFMA(a0, wi[0][0], av[0]); av[1] = MFMA(a0, wi[1][0], av[1]);
  av[2] = MFMA(a0, wi[2][0], av[2]); av[3] = MFMA(a0, wi[3][0], av[3]);
  av[0] = MFMA(a1, wi[0][1], av[0]); av[1] = MFMA(a1, wi[1][1], av[1]);
  av[2] = MFMA(a1, wi[2][1], av[2]); av[3] = MFMA(a1, wi[3][1], av[3]);
  av[0] = MFMA(b0, wh[0][0], av[0]); av[1] = MFMA(b0, wh[1][0], av[1]);
  av[2] = MFMA(b0, wh[2][0], av[2]); av[3] = MFMA(b0, wh[3][0], av[3]);
  av[0] = MFMA(b1, wh[0][1], av[0]); av[1] = MFMA(b1, wh[1][1], av[1]);
  av[2] = MFMA(b1, wh[2][1], av[2]); av[3] = MFMA(b1, wh[3][1], av[3]);
  if (lane < 16){
#pragma unroll
    for (int r = 0; r < 4; ++r){
      float4v t_ = {av[0][r], av[1][r], av[2][r], av[3][r]};
      *(float4v*)&tp[lane][r*4] = t_;
    }
  }
  float4v g4 = *(const float4v*)&tp[c][kg*4];
  float hv = gates1(g4[0]+bs[0], g4[1]+bs[1], g4[2]+bs[2], g4[3]+bs[3], cst);
  h1s[TPAR][kg][wl*16 + c] = __float2bfloat16(hv);
  if (last) hfin[kg][wl*16 + c] = hv;
}

__global__ __launch_bounds__(512, 1) void lstm_rec(
    const u32* __restrict__ xg,
    const float* __restrict__ Whh0, const float* __restrict__ bih0, const float* __restrict__ bhh0,
    const float* __restrict__ Wih1, const float* __restrict__ Whh1,
    const float* __restrict__ bih1, const float* __restrict__ bhh1,
    const float* __restrict__ fcw,  const float* __restrict__ fcb,
    float* __restrict__ out,
    float* __restrict__ cstate, u16* __restrict__ h0st, u16* __restrict__ h1st,
    int tb, int nt)
{
  const int tid  = threadIdx.x;
  const int lane = tid & 63;
  const int wv   = tid >> 6;
  const int grp  = wv >> 2;
  const int wl   = wv & 3;
  const int c    = lane & 15;
  const int kg   = lane >> 4;
  const int bblk = blockIdx.x;          // 4-batch block (0..255)

  __shared__ __align__(16) __hip_bfloat16 h0s[2][16][72];
  __shared__ __align__(16) __hip_bfloat16 h1s[2][16][72];
  __shared__ __align__(16) float tmp[2][4][16][20];
  __shared__ float hfin[4][64];

  { // zero h buffers (rows 4-15 must be zero ALWAYS)
    __hip_bfloat16 z = __float2bfloat16(0.f);
    for (int i = tid; i < 2*16*72; i += 512){
      (&h0s[0][0][0])[i] = z;
      (&h1s[0][0][0])[i] = z;
    }
  }
  __syncthreads();
  float cst = 0.f;
  if (tb > 0){
    if (tid < 256){
      ((u16*)&h0s[1][0][0])[(tid>>6)*72 + (tid&63)] = h0st[bblk*256 + tid];
      ((u16*)&h1s[0][0][0])[(tid>>6)*72 + (tid&63)] = h1st[bblk*256 + tid];
    }
    cst = cstate[(size_t)bblk*512 + tid];
  }

  // weights
  short8 wi[4][2], wh[4][2];
  float  bs[4];
  const int urow = wl*16 + c;
  if (grp == 0){
#pragma unroll
    for (int gt = 0; gt < 4; ++gt){
      const int row = gt*64 + urow;
#pragma unroll
      for (int kk = 0; kk < 2; ++kk)
        wh[gt][kk] = load_bf8(Whh0 + row*64 + kk*32 + kg*8);
      bs[gt] = bih0[row] + bhh0[row];
    }
  } else {
#pragma unroll
    for (int gt = 0; gt < 4; ++gt){
      const int row = gt*64 + urow;
#pragma unroll
      for (int kk = 0; kk < 2; ++kk){
        wi[gt][kk] = load_bf8(Wih1 + row*64 + kk*32 + kg*8);
        wh[gt][kk] = load_bf8(Whh1 + row*64 + kk*32 + kg*8);
      }
      bs[gt] = bih1[row] + bhh1[row];
    }
  }

  float (*tp)[20] = tmp[grp][wl];

  // xg ring, depth 4 (8 B/lane/step)
  const u32* xgw = nullptr;
  uint2v xc[4];
  if (grp == 0){
    xgw = xg + ((size_t)bblk*256 + wl*64 + lane)*2;
#pragma unroll
    for (int s = 0; s < 3; ++s)
      xc[s] = *(const uint2v*)(xgw + (size_t)s * XG_TSTRIDE);
  }

  __syncthreads();

  for (int lt = 0; lt < nt; lt += 4){
    if (grp == 0) l0_step<0>(lt, nt, xgw, xc, wh, bs, cst, h0s, tp, lane, c, kg, wl);
    else if (tb + lt > 0) l1_step<1>(false, wi, wh, bs, cst, h0s, h1s, tp, hfin, lane, c, kg, wl);
    PIPE_BARRIER();
    if (grp == 0) l0_step<1>(lt, nt, xgw, xc, wh, bs, cst, h0s, tp, lane, c, kg, wl);
    else          l1_step<0>(false, wi, wh, bs, cst, h0s, h1s, tp, hfin, lane, c, kg, wl);
    PIPE_BARRIER();
    if (grp == 0) l0_step<2>(lt, nt, xgw, xc, wh, bs, cst, h0s, tp, lane, c, kg, wl);
    else          l1_step<1>(false, wi, wh, bs, cst, h0s, h1s, tp, hfin, lane, c, kg, wl);
    PIPE_BARRIER();
    if (grp == 0) l0_step<3>(lt, nt, xgw, xc, wh, bs, cst, h0s, tp, lane, c, kg, wl);
    else          l1_step<0>(false, wi, wh, bs, cst, h0s, h1s, tp, hfin, lane, c, kg, wl);
    PIPE_BARRIER();
  }
  // epilogue on last chunk: t1 = 511 (odd parity)
  if (grp == 1 && tb + nt == 512)
    l1_step<1>(true, wi, wh, bs, cst, h0s, h1s, tp, hfin, lane, c, kg, wl);
  __syncthreads();

  if (tb + nt < 512){
    if (tid < 256){
      h0st[bblk*256 + tid] = ((const u16*)&h0s[1][0][0])[(tid>>6)*72 + (tid&63)];
      h1st[bblk*256 + tid] = ((const u16*)&h1s[0][0][0])[(tid>>6)*72 + (tid&63)];
    }
    cstate[(size_t)bblk*512 + tid] = cst;
  } else if (tid < 4){
    float s = fcb[0];
#pragma unroll
    for (int k = 0; k < 64; ++k) s += hfin[tid][k] * fcw[k];
    out[bblk*4 + tid] = frcp(1.f + fexp2(-LOG2E * s));
  }
}

extern "C" void kernel_launch(void* const* d_in, const int* in_sizes, int n_in,
                              void* d_out, int out_size, void* d_ws, size_t ws_size,
                              hipStream_t stream) {
  const float* x    = (const float*)d_in[0];
  const float* Wih0 = (const float*)d_in[1];
  const float* Whh0 = (const float*)d_in[2];
  const float* bih0 = (const float*)d_in[3];
  const float* bhh0 = (const float*)d_in[4];
  const float* Wih1 = (const float*)d_in[5];
  const float* Whh1 = (const float*)d_in[6];
  const float* bih1 = (const float*)d_in[7];
  const float* bhh1 = (const float*)d_in[8];
  const float* fcw  = (const float*)d_in[9];
  const float* fcb  = (const float*)d_in[10];
  float* out = (float*)d_out;

  const size_t perT = 1024ull * 256 * 2;   // 512 KB per t
  int CT = 512;
  while (CT > 8 && (size_t)CT * perT + (1u << 20) > ws_size) CT >>= 1;

  u32* xg = (u32*)d_ws;
  char* sb = (char*)d_ws + (size_t)CT * perT;
  float* cstate = (float*)sb;                       // 512 KB
  u16*   h0st   = (u16*)(sb + (512u << 10));        // 128 KB
  u16*   h1st   = (u16*)(sb + (512u << 10) + (128u << 10));

  for (int tb = 0; tb < 512; tb += CT){
    hipLaunchKernelGGL(xg_gemm, dim3(CT/8, 64), dim3(512), 0, stream,
                       x, Wih0, xg, tb);
    hipLaunchKernelGGL(lstm_rec, dim3(256), dim3(512), 0, stream,
                       xg, Whh0, bih0, bhh0, Wih1, Whh1, bih1, bhh1,
                       fcw, fcb, out, cstate, h0st, h1st, tb, CT);
  }
}